// Round 1
// baseline (537.609 us; speedup 1.0000x reference)
//
#include <hip/hip_runtime.h>
#include <hip/hip_bf16.h>

#define NN 100000
#define NE 1600000

// ---------------------------------------------------------------------------
// Build CSR row_ptr from sorted edge_row. row_ptr[i] = first e with row[e]>=i.
// ---------------------------------------------------------------------------
__global__ __launch_bounds__(256) void build_rowptr(const int* __restrict__ row,
                                                    int* __restrict__ row_ptr,
                                                    int E, int N) {
    int e = blockIdx.x * blockDim.x + threadIdx.x;
    if (e >= E) return;
    int r  = row[e];
    int rp = (e == 0) ? -1 : row[e - 1];
    for (int i = rp + 1; i <= r; ++i) row_ptr[i] = e;
    if (e == E - 1) {
        for (int i = r + 1; i <= N; ++i) row_ptr[i] = E;
    }
}

// dinv[i] = deg>0 ? rsqrt(deg) : 0   (deg = row_ptr[i+1]-row_ptr[i])
__global__ __launch_bounds__(256) void compute_dinv(const int* __restrict__ row_ptr,
                                                    float* __restrict__ dinv, int N) {
    int i = blockIdx.x * blockDim.x + threadIdx.x;
    if (i >= N) return;
    int deg = row_ptr[i + 1] - row_ptr[i];
    dinv[i] = (deg > 0) ? rsqrtf((float)deg) : 0.0f;
}

// ---------------------------------------------------------------------------
// Tiled fp32 GEMM: out[M,N] = X[M,K] @ W[K,N] + bias.
// 256 threads, 4x4 microtile per thread. W staged in KC-row chunks in LDS.
// N=128: BM=32 rows/block, LDS = 32KB(W)+16KB(X)=48KB.
// N=64 : BM=64 rows/block, LDS = 16KB(W)+32KB(X)=48KB.
// ---------------------------------------------------------------------------
template <int N, int K, int KC>
__global__ __launch_bounds__(256) void gemm_kernel(const float* __restrict__ X,
                                                   const float* __restrict__ W,
                                                   const float* __restrict__ bias,
                                                   float* __restrict__ out, int M) {
    constexpr int C4 = N / 4;        // float4 columns
    constexpr int G  = 256 / C4;     // row groups
    constexpr int BM = 4 * G;        // rows per block
    __shared__ float Wl[KC * N];
    __shared__ float Xl[BM * K];

    const int t = threadIdx.x;
    const int c = t % C4;            // this thread's float4 column
    const int g = t / C4;            // this thread's row group (4 rows)
    const int rbase = blockIdx.x * BM;

    // stage X tile (BM x K), zero-pad tail rows
    const int valid_rows = (M - rbase < BM) ? (M - rbase) : BM;
    const int xcount = valid_rows * K / 4;
    const float4* xsrc = (const float4*)(X + (size_t)rbase * K);
    for (int i = t; i < BM * K / 4; i += 256) {
        ((float4*)Xl)[i] = (i < xcount) ? xsrc[i] : make_float4(0.f, 0.f, 0.f, 0.f);
    }

    float acc[4][4];
    float4 bv = ((const float4*)bias)[c];
#pragma unroll
    for (int jr = 0; jr < 4; ++jr) {
        acc[jr][0] = bv.x; acc[jr][1] = bv.y; acc[jr][2] = bv.z; acc[jr][3] = bv.w;
    }

    for (int kc = 0; kc < K; kc += KC) {
        __syncthreads();   // protects Wl reuse (and Xl on first pass)
        for (int i = t; i < KC * N / 4; i += 256)
            ((float4*)Wl)[i] = ((const float4*)(W + (size_t)kc * N))[i];
        __syncthreads();

#pragma unroll 4
        for (int k = 0; k < KC; k += 4) {
            float4 w0 = *(const float4*)&Wl[(k + 0) * N + 4 * c];
            float4 w1 = *(const float4*)&Wl[(k + 1) * N + 4 * c];
            float4 w2 = *(const float4*)&Wl[(k + 2) * N + 4 * c];
            float4 w3 = *(const float4*)&Wl[(k + 3) * N + 4 * c];
#pragma unroll
            for (int jr = 0; jr < 4; ++jr) {
                float4 xv = *(const float4*)&Xl[(g * 4 + jr) * K + kc + k];
                acc[jr][0] += xv.x * w0.x + xv.y * w1.x + xv.z * w2.x + xv.w * w3.x;
                acc[jr][1] += xv.x * w0.y + xv.y * w1.y + xv.z * w2.y + xv.w * w3.y;
                acc[jr][2] += xv.x * w0.z + xv.y * w1.z + xv.z * w2.z + xv.w * w3.z;
                acc[jr][3] += xv.x * w0.w + xv.y * w1.w + xv.z * w2.w + xv.w * w3.w;
            }
        }
    }

#pragma unroll
    for (int jr = 0; jr < 4; ++jr) {
        int r = rbase + g * 4 + jr;
        if (r < M) {
            float4 o = make_float4(acc[jr][0], acc[jr][1], acc[jr][2], acc[jr][3]);
            *(float4*)&out[(size_t)r * N + 4 * c] = o;
        }
    }
}

// ---------------------------------------------------------------------------
// SpMM (CSR, wave-per-row), F=128, fused relu. lane l handles features 2l,2l+1.
// ---------------------------------------------------------------------------
__global__ __launch_bounds__(256) void spmm_relu_128(const int* __restrict__ row_ptr,
                                                     const int* __restrict__ col,
                                                     const float* __restrict__ dinv,
                                                     const float* __restrict__ H,
                                                     float* __restrict__ out, int N) {
    int wave = threadIdx.x >> 6;
    int lane = threadIdx.x & 63;
    int i = blockIdx.x * 4 + wave;
    if (i >= N) return;
    float di = dinv[i];
    int e0 = row_ptr[i], e1 = row_ptr[i + 1];
    float2 acc = make_float2(0.f, 0.f);
    for (int e = e0; e < e1; ++e) {
        int cc = col[e];
        float v = di * dinv[cc];
        float2 h = *(const float2*)&H[(size_t)cc * 128 + 2 * lane];
        acc.x += v * h.x;
        acc.y += v * h.y;
    }
    acc.x = fmaxf(acc.x, 0.f);
    acc.y = fmaxf(acc.y, 0.f);
    *(float2*)&out[(size_t)i * 128 + 2 * lane] = acc;
}

// ---------------------------------------------------------------------------
// SpMM (CSR, wave-per-row), F=64, fused log_softmax across the 64 lanes.
// ---------------------------------------------------------------------------
__global__ __launch_bounds__(256) void spmm_logsoftmax_64(const int* __restrict__ row_ptr,
                                                          const int* __restrict__ col,
                                                          const float* __restrict__ dinv,
                                                          const float* __restrict__ H,
                                                          float* __restrict__ out, int N) {
    int wave = threadIdx.x >> 6;
    int lane = threadIdx.x & 63;
    int i = blockIdx.x * 4 + wave;
    if (i >= N) return;
    float di = dinv[i];
    int e0 = row_ptr[i], e1 = row_ptr[i + 1];
    float acc = 0.f;
    for (int e = e0; e < e1; ++e) {
        int cc = col[e];
        float v = di * dinv[cc];
        acc += v * H[(size_t)cc * 64 + lane];
    }
    // log_softmax over 64 lanes
    float m = acc;
#pragma unroll
    for (int off = 32; off > 0; off >>= 1)
        m = fmaxf(m, __shfl_xor(m, off, 64));
    float ex = __expf(acc - m);
    float s = ex;
#pragma unroll
    for (int off = 32; off > 0; off >>= 1)
        s += __shfl_xor(s, off, 64);
    out[(size_t)i * 64 + lane] = acc - m - __logf(s);
}

// ---------------------------------------------------------------------------
extern "C" void kernel_launch(void* const* d_in, const int* in_sizes, int n_in,
                              void* d_out, int out_size, void* d_ws, size_t ws_size,
                              hipStream_t stream) {
    const float* x    = (const float*)d_in[0];
    const int*   erow = (const int*)d_in[1];
    const int*   ecol = (const int*)d_in[2];
    const float* W0   = (const float*)d_in[3];
    const float* b0   = (const float*)d_in[4];
    const float* W1   = (const float*)d_in[5];
    const float* b1   = (const float*)d_in[6];
    float* out = (float*)d_out;

    char* ws = (char*)d_ws;
    // layout: [row_ptr 0..1MB) [dinv 1..2MB) [h0 2MB..+51.2MB) [h1 ...+51.2MB)
    int*   row_ptr = (int*)ws;
    float* dinv    = (float*)(ws + (1u << 20));
    float* h0      = (float*)(ws + (2u << 20));                       // 100000*128 f32
    float* h1      = (float*)(ws + (2u << 20) + 51200000u);           // 100000*128 f32
    float* h2      = h0;                                              // reuse (100000*64 f32)

    // 1. CSR offsets from sorted edge_row
    build_rowptr<<<(NE + 255) / 256, 256, 0, stream>>>(erow, row_ptr, NE, NN);
    // 2. dinv
    compute_dinv<<<(NN + 255) / 256, 256, 0, stream>>>(row_ptr, dinv, NN);
    // 3. h0 = x @ W0 + b0      (BM=32 -> 3125 blocks)
    gemm_kernel<128, 128, 64><<<(NN + 31) / 32, 256, 0, stream>>>(x, W0, b0, h0, NN);
    // 4. h1 = relu(spmm(h0))
    spmm_relu_128<<<(NN + 3) / 4, 256, 0, stream>>>(row_ptr, ecol, dinv, h0, h1, NN);
    // 5. h2 = h1 @ W1 + b1     (BM=64 -> 1563 blocks)
    gemm_kernel<64, 128, 64><<<(NN + 63) / 64, 256, 0, stream>>>(h1, W1, b1, h2, NN);
    // 6. out = log_softmax(spmm(h2))
    spmm_logsoftmax_64<<<(NN + 3) / 4, 256, 0, stream>>>(row_ptr, ecol, dinv, h2, out, NN);
}

// Round 2
// 404.436 us; speedup vs baseline: 1.3293x; 1.3293x over previous
//
#include <hip/hip_runtime.h>
#include <hip/hip_bf16.h>

#define NN 100000
#define NE 1600000

// ---------------------------------------------------------------------------
// Build CSR row_ptr from sorted edge_row. row_ptr[i] = first e with row[e]>=i.
// ---------------------------------------------------------------------------
__global__ __launch_bounds__(256) void build_rowptr(const int* __restrict__ row,
                                                    int* __restrict__ row_ptr,
                                                    int E, int N) {
    int e = blockIdx.x * blockDim.x + threadIdx.x;
    if (e >= E) return;
    int r  = row[e];
    int rp = (e == 0) ? -1 : row[e - 1];
    for (int i = rp + 1; i <= r; ++i) row_ptr[i] = e;
    if (e == E - 1) {
        for (int i = r + 1; i <= N; ++i) row_ptr[i] = E;
    }
}

// dinv[i] = deg>0 ? rsqrt(deg) : 0   (deg = row_ptr[i+1]-row_ptr[i])
__global__ __launch_bounds__(256) void compute_dinv(const int* __restrict__ row_ptr,
                                                    float* __restrict__ dinv, int N) {
    int i = blockIdx.x * blockDim.x + threadIdx.x;
    if (i >= N) return;
    int deg = row_ptr[i + 1] - row_ptr[i];
    dinv[i] = (deg > 0) ? rsqrtf((float)deg) : 0.0f;
}

// ---------------------------------------------------------------------------
// Tiled fp32 GEMM: out[M,N] = X[M,K] @ W[K,N] + bias.  (unchanged from R1)
// ---------------------------------------------------------------------------
template <int N, int K, int KC>
__global__ __launch_bounds__(256) void gemm_kernel(const float* __restrict__ X,
                                                   const float* __restrict__ W,
                                                   const float* __restrict__ bias,
                                                   float* __restrict__ out, int M) {
    constexpr int C4 = N / 4;        // float4 columns
    constexpr int G  = 256 / C4;     // row groups
    constexpr int BM = 4 * G;        // rows per block
    __shared__ float Wl[KC * N];
    __shared__ float Xl[BM * K];

    const int t = threadIdx.x;
    const int c = t % C4;
    const int g = t / C4;
    const int rbase = blockIdx.x * BM;

    const int valid_rows = (M - rbase < BM) ? (M - rbase) : BM;
    const int xcount = valid_rows * K / 4;
    const float4* xsrc = (const float4*)(X + (size_t)rbase * K);
    for (int i = t; i < BM * K / 4; i += 256) {
        ((float4*)Xl)[i] = (i < xcount) ? xsrc[i] : make_float4(0.f, 0.f, 0.f, 0.f);
    }

    float acc[4][4];
    float4 bv = ((const float4*)bias)[c];
#pragma unroll
    for (int jr = 0; jr < 4; ++jr) {
        acc[jr][0] = bv.x; acc[jr][1] = bv.y; acc[jr][2] = bv.z; acc[jr][3] = bv.w;
    }

    for (int kc = 0; kc < K; kc += KC) {
        __syncthreads();
        for (int i = t; i < KC * N / 4; i += 256)
            ((float4*)Wl)[i] = ((const float4*)(W + (size_t)kc * N))[i];
        __syncthreads();

#pragma unroll 4
        for (int k = 0; k < KC; k += 4) {
            float4 w0 = *(const float4*)&Wl[(k + 0) * N + 4 * c];
            float4 w1 = *(const float4*)&Wl[(k + 1) * N + 4 * c];
            float4 w2 = *(const float4*)&Wl[(k + 2) * N + 4 * c];
            float4 w3 = *(const float4*)&Wl[(k + 3) * N + 4 * c];
#pragma unroll
            for (int jr = 0; jr < 4; ++jr) {
                float4 xv = *(const float4*)&Xl[(g * 4 + jr) * K + kc + k];
                acc[jr][0] += xv.x * w0.x + xv.y * w1.x + xv.z * w2.x + xv.w * w3.x;
                acc[jr][1] += xv.x * w0.y + xv.y * w1.y + xv.z * w2.y + xv.w * w3.y;
                acc[jr][2] += xv.x * w0.z + xv.y * w1.z + xv.z * w2.z + xv.w * w3.z;
                acc[jr][3] += xv.x * w0.w + xv.y * w1.w + xv.z * w2.w + xv.w * w3.w;
            }
        }
    }

#pragma unroll
    for (int jr = 0; jr < 4; ++jr) {
        int r = rbase + g * 4 + jr;
        if (r < M) {
            float4 o = make_float4(acc[jr][0], acc[jr][1], acc[jr][2], acc[jr][3]);
            *(float4*)&out[(size_t)r * N + 4 * c] = o;
        }
    }
}

// ---------------------------------------------------------------------------
// SpMM (CSR, wave-per-row), F=128, fused relu.
// Edge loop unrolled x4: 4 independent row gathers in flight per wave.
// ---------------------------------------------------------------------------
__global__ __launch_bounds__(256) void spmm_relu_128(const int* __restrict__ row_ptr,
                                                     const int* __restrict__ col,
                                                     const float* __restrict__ dinv,
                                                     const float* __restrict__ H,
                                                     float* __restrict__ out, int N) {
    int wave = threadIdx.x >> 6;
    int lane = threadIdx.x & 63;
    int i = blockIdx.x * 4 + wave;
    if (i >= N) return;
    float di = dinv[i];
    int e0 = row_ptr[i], e1 = row_ptr[i + 1];
    float accx = 0.f, accy = 0.f;
    int e = e0;
    for (; e + 4 <= e1; e += 4) {
        int c0 = col[e + 0], c1 = col[e + 1], c2 = col[e + 2], c3 = col[e + 3];
        float v0 = dinv[c0], v1 = dinv[c1], v2 = dinv[c2], v3 = dinv[c3];
        float2 h0 = *(const float2*)&H[(size_t)c0 * 128 + 2 * lane];
        float2 h1 = *(const float2*)&H[(size_t)c1 * 128 + 2 * lane];
        float2 h2 = *(const float2*)&H[(size_t)c2 * 128 + 2 * lane];
        float2 h3 = *(const float2*)&H[(size_t)c3 * 128 + 2 * lane];
        accx += v0 * h0.x + v1 * h1.x + v2 * h2.x + v3 * h3.x;
        accy += v0 * h0.y + v1 * h1.y + v2 * h2.y + v3 * h3.y;
    }
    for (; e < e1; ++e) {
        int cc = col[e];
        float v = dinv[cc];
        float2 h = *(const float2*)&H[(size_t)cc * 128 + 2 * lane];
        accx += v * h.x;
        accy += v * h.y;
    }
    accx = fmaxf(accx * di, 0.f);
    accy = fmaxf(accy * di, 0.f);
    *(float2*)&out[(size_t)i * 128 + 2 * lane] = make_float2(accx, accy);
}

// ---------------------------------------------------------------------------
// SpMM (CSR, wave-per-row), F=64, fused log_softmax. Edge loop unrolled x4.
// ---------------------------------------------------------------------------
__global__ __launch_bounds__(256) void spmm_logsoftmax_64(const int* __restrict__ row_ptr,
                                                          const int* __restrict__ col,
                                                          const float* __restrict__ dinv,
                                                          const float* __restrict__ H,
                                                          float* __restrict__ out, int N) {
    int wave = threadIdx.x >> 6;
    int lane = threadIdx.x & 63;
    int i = blockIdx.x * 4 + wave;
    if (i >= N) return;
    float di = dinv[i];
    int e0 = row_ptr[i], e1 = row_ptr[i + 1];
    float acc = 0.f;
    int e = e0;
    for (; e + 4 <= e1; e += 4) {
        int c0 = col[e + 0], c1 = col[e + 1], c2 = col[e + 2], c3 = col[e + 3];
        float v0 = dinv[c0], v1 = dinv[c1], v2 = dinv[c2], v3 = dinv[c3];
        float h0 = H[(size_t)c0 * 64 + lane];
        float h1 = H[(size_t)c1 * 64 + lane];
        float h2 = H[(size_t)c2 * 64 + lane];
        float h3 = H[(size_t)c3 * 64 + lane];
        acc += v0 * h0 + v1 * h1 + v2 * h2 + v3 * h3;
    }
    for (; e < e1; ++e) {
        int cc = col[e];
        acc += dinv[cc] * H[(size_t)cc * 64 + lane];
    }
    acc *= di;
    // log_softmax over 64 lanes
    float m = acc;
#pragma unroll
    for (int off = 32; off > 0; off >>= 1)
        m = fmaxf(m, __shfl_xor(m, off, 64));
    float ex = __expf(acc - m);
    float s = ex;
#pragma unroll
    for (int off = 32; off > 0; off >>= 1)
        s += __shfl_xor(s, off, 64);
    out[(size_t)i * 64 + lane] = acc - m - __logf(s);
}

// ---------------------------------------------------------------------------
extern "C" void kernel_launch(void* const* d_in, const int* in_sizes, int n_in,
                              void* d_out, int out_size, void* d_ws, size_t ws_size,
                              hipStream_t stream) {
    const float* x    = (const float*)d_in[0];
    const int*   erow = (const int*)d_in[1];
    const int*   ecol = (const int*)d_in[2];
    const float* W0   = (const float*)d_in[3];
    const float* b0   = (const float*)d_in[4];
    const float* W1   = (const float*)d_in[5];
    const float* b1   = (const float*)d_in[6];
    float* out = (float*)d_out;

    char* ws = (char*)d_ws;
    // layout: [row_ptr 0..1MB) [dinv 1..2MB) [h0 2MB..+51.2MB) [h1 ...+51.2MB)
    int*   row_ptr = (int*)ws;
    float* dinv    = (float*)(ws + (1u << 20));
    float* h0      = (float*)(ws + (2u << 20));                       // 100000*128 f32
    float* h1      = (float*)(ws + (2u << 20) + 51200000u);           // 100000*128 f32
    float* h2      = h0;                                              // reuse (100000*64 f32)

    build_rowptr<<<(NE + 255) / 256, 256, 0, stream>>>(erow, row_ptr, NE, NN);
    compute_dinv<<<(NN + 255) / 256, 256, 0, stream>>>(row_ptr, dinv, NN);
    gemm_kernel<128, 128, 64><<<(NN + 31) / 32, 256, 0, stream>>>(x, W0, b0, h0, NN);
    spmm_relu_128<<<(NN + 3) / 4, 256, 0, stream>>>(row_ptr, ecol, dinv, h0, h1, NN);
    gemm_kernel<64, 128, 64><<<(NN + 63) / 64, 256, 0, stream>>>(h1, W1, b1, h2, NN);
    spmm_logsoftmax_64<<<(NN + 3) / 4, 256, 0, stream>>>(row_ptr, ecol, dinv, h2, out, NN);
}

// Round 3
// 357.751 us; speedup vs baseline: 1.5027x; 1.1305x over previous
//
#include <hip/hip_runtime.h>
#include <hip/hip_bf16.h>

#define NN 100000
#define NE 1600000

// ---------------------------------------------------------------------------
// Build CSR row_ptr from sorted edge_row. row_ptr[i] = first e with row[e]>=i.
// ---------------------------------------------------------------------------
__global__ __launch_bounds__(256) void build_rowptr(const int* __restrict__ row,
                                                    int* __restrict__ row_ptr,
                                                    int E, int N) {
    int e = blockIdx.x * blockDim.x + threadIdx.x;
    if (e >= E) return;
    int r  = row[e];
    int rp = (e == 0) ? -1 : row[e - 1];
    for (int i = rp + 1; i <= r; ++i) row_ptr[i] = e;
    if (e == E - 1) {
        for (int i = r + 1; i <= N; ++i) row_ptr[i] = E;
    }
}

// dinv[i] = deg>0 ? rsqrt(deg) : 0   (deg = row_ptr[i+1]-row_ptr[i])
__global__ __launch_bounds__(256) void compute_dinv(const int* __restrict__ row_ptr,
                                                    float* __restrict__ dinv, int N) {
    int i = blockIdx.x * blockDim.x + threadIdx.x;
    if (i >= N) return;
    int deg = row_ptr[i + 1] - row_ptr[i];
    dinv[i] = (deg > 0) ? rsqrtf((float)deg) : 0.0f;
}

// ---------------------------------------------------------------------------
// Output store helpers: fp32 or bf16 (RNE) epilogue.
// ---------------------------------------------------------------------------
__device__ inline void store_out4(float* p, float4 v) { *(float4*)p = v; }
__device__ inline void store_out4(__hip_bfloat16* p, float4 v) {
    __hip_bfloat162 lo = __float22bfloat162_rn(make_float2(v.x, v.y));
    __hip_bfloat162 hi = __float22bfloat162_rn(make_float2(v.z, v.w));
    *(__hip_bfloat162*)(p)     = lo;
    *(__hip_bfloat162*)(p + 2) = hi;
}

// ---------------------------------------------------------------------------
// Tiled fp32 GEMM: out[M,N] = X[M,K] @ W[K,N] + bias. OutT = float or bf16.
// ---------------------------------------------------------------------------
template <int N, int K, int KC, typename OutT>
__global__ __launch_bounds__(256) void gemm_kernel(const float* __restrict__ X,
                                                   const float* __restrict__ W,
                                                   const float* __restrict__ bias,
                                                   OutT* __restrict__ out, int M) {
    constexpr int C4 = N / 4;        // float4 columns
    constexpr int G  = 256 / C4;     // row groups
    constexpr int BM = 4 * G;        // rows per block
    __shared__ float Wl[KC * N];
    __shared__ float Xl[BM * K];

    const int t = threadIdx.x;
    const int c = t % C4;
    const int g = t / C4;
    const int rbase = blockIdx.x * BM;

    const int valid_rows = (M - rbase < BM) ? (M - rbase) : BM;
    const int xcount = valid_rows * K / 4;
    const float4* xsrc = (const float4*)(X + (size_t)rbase * K);
    for (int i = t; i < BM * K / 4; i += 256) {
        ((float4*)Xl)[i] = (i < xcount) ? xsrc[i] : make_float4(0.f, 0.f, 0.f, 0.f);
    }

    float acc[4][4];
    float4 bv = ((const float4*)bias)[c];
#pragma unroll
    for (int jr = 0; jr < 4; ++jr) {
        acc[jr][0] = bv.x; acc[jr][1] = bv.y; acc[jr][2] = bv.z; acc[jr][3] = bv.w;
    }

    for (int kc = 0; kc < K; kc += KC) {
        __syncthreads();
        for (int i = t; i < KC * N / 4; i += 256)
            ((float4*)Wl)[i] = ((const float4*)(W + (size_t)kc * N))[i];
        __syncthreads();

#pragma unroll 4
        for (int k = 0; k < KC; k += 4) {
            float4 w0 = *(const float4*)&Wl[(k + 0) * N + 4 * c];
            float4 w1 = *(const float4*)&Wl[(k + 1) * N + 4 * c];
            float4 w2 = *(const float4*)&Wl[(k + 2) * N + 4 * c];
            float4 w3 = *(const float4*)&Wl[(k + 3) * N + 4 * c];
#pragma unroll
            for (int jr = 0; jr < 4; ++jr) {
                float4 xv = *(const float4*)&Xl[(g * 4 + jr) * K + kc + k];
                acc[jr][0] += xv.x * w0.x + xv.y * w1.x + xv.z * w2.x + xv.w * w3.x;
                acc[jr][1] += xv.x * w0.y + xv.y * w1.y + xv.z * w2.y + xv.w * w3.y;
                acc[jr][2] += xv.x * w0.z + xv.y * w1.z + xv.z * w2.z + xv.w * w3.z;
                acc[jr][3] += xv.x * w0.w + xv.y * w1.w + xv.z * w2.w + xv.w * w3.w;
            }
        }
    }

#pragma unroll
    for (int jr = 0; jr < 4; ++jr) {
        int r = rbase + g * 4 + jr;
        if (r < M) {
            float4 o = make_float4(acc[jr][0], acc[jr][1], acc[jr][2], acc[jr][3]);
            store_out4(&out[(size_t)r * N + 4 * c], o);
        }
    }
}

// ---------------------------------------------------------------------------
// SpMM (CSR, wave-per-row), F=128, bf16 H, fused relu, fp32 out.
// lane l reads one uint32 = features {2l, 2l+1}. Edge loop unrolled x4.
// ---------------------------------------------------------------------------
__global__ __launch_bounds__(256) void spmm_relu_128(const int* __restrict__ row_ptr,
                                                     const int* __restrict__ col,
                                                     const float* __restrict__ dinv,
                                                     const unsigned int* __restrict__ H, // bf16x2
                                                     float* __restrict__ out, int N) {
    int wave = threadIdx.x >> 6;
    int lane = threadIdx.x & 63;
    int i = blockIdx.x * 4 + wave;
    if (i >= N) return;
    float di = dinv[i];
    int e0 = row_ptr[i], e1 = row_ptr[i + 1];
    float accx = 0.f, accy = 0.f;
    int e = e0;
    for (; e + 4 <= e1; e += 4) {
        int c0 = col[e + 0], c1 = col[e + 1], c2 = col[e + 2], c3 = col[e + 3];
        float v0 = dinv[c0], v1 = dinv[c1], v2 = dinv[c2], v3 = dinv[c3];
        unsigned int u0 = H[(size_t)c0 * 64 + lane];
        unsigned int u1 = H[(size_t)c1 * 64 + lane];
        unsigned int u2 = H[(size_t)c2 * 64 + lane];
        unsigned int u3 = H[(size_t)c3 * 64 + lane];
        accx += v0 * __uint_as_float(u0 << 16) + v1 * __uint_as_float(u1 << 16)
              + v2 * __uint_as_float(u2 << 16) + v3 * __uint_as_float(u3 << 16);
        accy += v0 * __uint_as_float(u0 & 0xffff0000u) + v1 * __uint_as_float(u1 & 0xffff0000u)
              + v2 * __uint_as_float(u2 & 0xffff0000u) + v3 * __uint_as_float(u3 & 0xffff0000u);
    }
    for (; e < e1; ++e) {
        int cc = col[e];
        float v = dinv[cc];
        unsigned int u = H[(size_t)cc * 64 + lane];
        accx += v * __uint_as_float(u << 16);
        accy += v * __uint_as_float(u & 0xffff0000u);
    }
    accx = fmaxf(accx * di, 0.f);
    accy = fmaxf(accy * di, 0.f);
    *(float2*)&out[(size_t)i * 128 + 2 * lane] = make_float2(accx, accy);
}

// ---------------------------------------------------------------------------
// SpMM (CSR, wave-per-row), F=64, bf16 H, fused log_softmax, fp32 out.
// ---------------------------------------------------------------------------
__global__ __launch_bounds__(256) void spmm_logsoftmax_64(const int* __restrict__ row_ptr,
                                                          const int* __restrict__ col,
                                                          const float* __restrict__ dinv,
                                                          const unsigned short* __restrict__ H, // bf16
                                                          float* __restrict__ out, int N) {
    int wave = threadIdx.x >> 6;
    int lane = threadIdx.x & 63;
    int i = blockIdx.x * 4 + wave;
    if (i >= N) return;
    float di = dinv[i];
    int e0 = row_ptr[i], e1 = row_ptr[i + 1];
    float acc = 0.f;
    int e = e0;
    for (; e + 4 <= e1; e += 4) {
        int c0 = col[e + 0], c1 = col[e + 1], c2 = col[e + 2], c3 = col[e + 3];
        float v0 = dinv[c0], v1 = dinv[c1], v2 = dinv[c2], v3 = dinv[c3];
        float h0 = __uint_as_float((unsigned int)H[(size_t)c0 * 64 + lane] << 16);
        float h1 = __uint_as_float((unsigned int)H[(size_t)c1 * 64 + lane] << 16);
        float h2 = __uint_as_float((unsigned int)H[(size_t)c2 * 64 + lane] << 16);
        float h3 = __uint_as_float((unsigned int)H[(size_t)c3 * 64 + lane] << 16);
        acc += v0 * h0 + v1 * h1 + v2 * h2 + v3 * h3;
    }
    for (; e < e1; ++e) {
        int cc = col[e];
        acc += dinv[cc] * __uint_as_float((unsigned int)H[(size_t)cc * 64 + lane] << 16);
    }
    acc *= di;
    // log_softmax over 64 lanes
    float m = acc;
#pragma unroll
    for (int off = 32; off > 0; off >>= 1)
        m = fmaxf(m, __shfl_xor(m, off, 64));
    float ex = __expf(acc - m);
    float s = ex;
#pragma unroll
    for (int off = 32; off > 0; off >>= 1)
        s += __shfl_xor(s, off, 64);
    out[(size_t)i * 64 + lane] = acc - m - __logf(s);
}

// ---------------------------------------------------------------------------
extern "C" void kernel_launch(void* const* d_in, const int* in_sizes, int n_in,
                              void* d_out, int out_size, void* d_ws, size_t ws_size,
                              hipStream_t stream) {
    const float* x    = (const float*)d_in[0];
    const int*   erow = (const int*)d_in[1];
    const int*   ecol = (const int*)d_in[2];
    const float* W0   = (const float*)d_in[3];
    const float* b0   = (const float*)d_in[4];
    const float* W1   = (const float*)d_in[5];
    const float* b1   = (const float*)d_in[6];
    float* out = (float*)d_out;

    char* ws = (char*)d_ws;
    // layout (bytes):
    //   [0, 512K)        row_ptr (100001 ints)
    //   [512K, 1M)       dinv (100000 f32)
    //   [1M, +25.6M)     h0b  bf16 100000*128
    //   [27M, +51.2M)    h1   f32  100000*128
    //   [79M, +12.8M)    h2b  bf16 100000*64
    int*             row_ptr = (int*)ws;
    float*           dinv    = (float*)(ws + (512u << 10));
    __hip_bfloat16*  h0b     = (__hip_bfloat16*)(ws + (1u << 20));
    float*           h1      = (float*)(ws + 27000000u);
    __hip_bfloat16*  h2b     = (__hip_bfloat16*)(ws + 79000000u);

    build_rowptr<<<(NE + 255) / 256, 256, 0, stream>>>(erow, row_ptr, NE, NN);
    compute_dinv<<<(NN + 255) / 256, 256, 0, stream>>>(row_ptr, dinv, NN);
    // h0b = bf16(x @ W0 + b0)
    gemm_kernel<128, 128, 64, __hip_bfloat16><<<(NN + 31) / 32, 256, 0, stream>>>(x, W0, b0, h0b, NN);
    // h1 = relu(spmm(h0b))  (fp32)
    spmm_relu_128<<<(NN + 3) / 4, 256, 0, stream>>>(row_ptr, ecol, dinv,
                                                    (const unsigned int*)h0b, h1, NN);
    // h2b = bf16(h1 @ W1 + b1)
    gemm_kernel<64, 128, 64, __hip_bfloat16><<<(NN + 63) / 64, 256, 0, stream>>>(h1, W1, b1, h2b, NN);
    // out = log_softmax(spmm(h2b))
    spmm_logsoftmax_64<<<(NN + 3) / 4, 256, 0, stream>>>(row_ptr, ecol, dinv,
                                                         (const unsigned short*)h2b, out, NN);
}

// Round 4
// 282.634 us; speedup vs baseline: 1.9021x; 1.2658x over previous
//
#include <hip/hip_runtime.h>
#include <hip/hip_bf16.h>

#define NN 100000
#define NE 1600000

typedef __bf16 bf16x8 __attribute__((ext_vector_type(8)));
typedef float  f32x4  __attribute__((ext_vector_type(4)));

// ---------------------------------------------------------------------------
// Build CSR row_ptr from sorted edge_row. row_ptr[i] = first e with row[e]>=i.
// ---------------------------------------------------------------------------
__global__ __launch_bounds__(256) void build_rowptr(const int* __restrict__ row,
                                                    int* __restrict__ row_ptr,
                                                    int E, int N) {
    int e = blockIdx.x * blockDim.x + threadIdx.x;
    if (e >= E) return;
    int r  = row[e];
    int rp = (e == 0) ? -1 : row[e - 1];
    for (int i = rp + 1; i <= r; ++i) row_ptr[i] = e;
    if (e == E - 1) {
        for (int i = r + 1; i <= N; ++i) row_ptr[i] = E;
    }
}

// dinv[i] = deg>0 ? rsqrt(deg) : 0
__global__ __launch_bounds__(256) void compute_dinv(const int* __restrict__ row_ptr,
                                                    float* __restrict__ dinv, int N) {
    int i = blockIdx.x * blockDim.x + threadIdx.x;
    if (i >= N) return;
    int deg = row_ptr[i + 1] - row_ptr[i];
    dinv[i] = (deg > 0) ? rsqrtf((float)deg) : 0.0f;
}

// Wt[n][k] = bf16(W[k][n])  — B-operand layout, k contiguous.
__global__ __launch_bounds__(256) void pack_wt(const float* __restrict__ W,
                                               __hip_bfloat16* __restrict__ Wt,
                                               int K, int N) {
    int idx = blockIdx.x * 256 + threadIdx.x;
    if (idx >= K * N) return;
    int n = idx / K, k = idx - n * K;
    Wt[idx] = __float2bfloat16(W[(size_t)k * N + n]);
}

// ---------------------------------------------------------------------------
// MFMA bf16 GEMM: out[M,NO] = bf16(X[M,128]) @ Wt^T + bias, out bf16.
// Block: 256 thr / 4 waves, BM=64 rows. Wave w: rows w*16..+16, all NO cols.
// LDS rows padded to 136 shorts (272B) -> frag ds_read_b128 ~2-way conflicts.
// Fragment layouts (m89-verified): A[m=lane&15][k=quad*8+j],
// B[n=lane&15][k=quad*8+j], C[row=quad*4+reg][col=lane&15].
// ---------------------------------------------------------------------------
template <int NO, typename InT>
__global__ __launch_bounds__(256) void gemm_mfma(const InT* __restrict__ X,
                                                 const __hip_bfloat16* __restrict__ Wt,
                                                 const float* __restrict__ bias,
                                                 __hip_bfloat16* __restrict__ out, int M) {
    constexpr int LDA = 136;     // padded LDS row stride (shorts)
    constexpr int NT  = NO / 16; // n-tiles per wave
    __shared__ short As[64 * LDA];
    __shared__ short Ws[NO * LDA];

    const int t = threadIdx.x;
    const int w = t >> 6, lane = t & 63;
    const int l15 = lane & 15, quad = lane >> 4;
    const int rbase = blockIdx.x * 64;

    // stage Wt (NO x 128 bf16) -> Ws
    for (int i = t; i < NO * 16; i += 256) {
        int n = i >> 4, c8 = (i & 15) << 3;
        *(uint4*)&Ws[n * LDA + c8] = ((const uint4*)Wt)[i];
    }
    // stage A tile (64 x 128) -> As (bf16)
    if constexpr (sizeof(InT) == 4) {
        for (int i = t; i < 2048; i += 256) {       // 64 rows x 32 float4
            int r = i >> 5, c = (i & 31) << 2;      // c in shorts
            float4 xv = make_float4(0.f, 0.f, 0.f, 0.f);
            if (rbase + r < M) xv = ((const float4*)X)[(size_t)rbase * 32 + i];
            union { __hip_bfloat162 h; unsigned int u; } p0, p1;
            p0.h = __float22bfloat162_rn(make_float2(xv.x, xv.y));
            p1.h = __float22bfloat162_rn(make_float2(xv.z, xv.w));
            *(uint2*)&As[r * LDA + c] = make_uint2(p0.u, p1.u);
        }
    } else {
        for (int i = t; i < 1024; i += 256) {       // 64 rows x 16 uint4
            int r = i >> 4, c8 = (i & 15) << 3;
            uint4 v = make_uint4(0u, 0u, 0u, 0u);
            if (rbase + r < M) v = ((const uint4*)X)[(size_t)rbase * 16 + i];
            *(uint4*)&As[r * LDA + c8] = v;
        }
    }
    __syncthreads();

    f32x4 acc[NT];
#pragma unroll
    for (int nt = 0; nt < NT; ++nt) {
        float bv = bias[nt * 16 + l15];
        acc[nt][0] = bv; acc[nt][1] = bv; acc[nt][2] = bv; acc[nt][3] = bv;
    }

    const int arow = w * 16 + l15;
#pragma unroll
    for (int kc = 0; kc < 4; ++kc) {
        bf16x8 af = *(const bf16x8*)&As[arow * LDA + kc * 32 + quad * 8];
#pragma unroll
        for (int nt = 0; nt < NT; ++nt) {
            bf16x8 bfr = *(const bf16x8*)&Ws[(nt * 16 + l15) * LDA + kc * 32 + quad * 8];
            acc[nt] = __builtin_amdgcn_mfma_f32_16x16x32_bf16(af, bfr, acc[nt], 0, 0, 0);
        }
    }

#pragma unroll
    for (int nt = 0; nt < NT; ++nt) {
#pragma unroll
        for (int r = 0; r < 4; ++r) {
            int grow = rbase + w * 16 + quad * 4 + r;
            if (grow < M)
                out[(size_t)grow * NO + nt * 16 + l15] = __float2bfloat16(acc[nt][r]);
        }
    }
}

// ---------------------------------------------------------------------------
// SpMM (CSR, wave-per-row), F=128, bf16 H, fused relu, bf16 out.
// ---------------------------------------------------------------------------
__global__ __launch_bounds__(256) void spmm_relu_128(const int* __restrict__ row_ptr,
                                                     const int* __restrict__ col,
                                                     const float* __restrict__ dinv,
                                                     const unsigned int* __restrict__ H, // bf16x2
                                                     __hip_bfloat16* __restrict__ out, int N) {
    int wave = threadIdx.x >> 6;
    int lane = threadIdx.x & 63;
    int i = blockIdx.x * 4 + wave;
    if (i >= N) return;
    float di = dinv[i];
    int e0 = row_ptr[i], e1 = row_ptr[i + 1];
    float accx = 0.f, accy = 0.f;
    int e = e0;
    for (; e + 4 <= e1; e += 4) {
        int c0 = col[e + 0], c1 = col[e + 1], c2 = col[e + 2], c3 = col[e + 3];
        float v0 = dinv[c0], v1 = dinv[c1], v2 = dinv[c2], v3 = dinv[c3];
        unsigned int u0 = H[(size_t)c0 * 64 + lane];
        unsigned int u1 = H[(size_t)c1 * 64 + lane];
        unsigned int u2 = H[(size_t)c2 * 64 + lane];
        unsigned int u3 = H[(size_t)c3 * 64 + lane];
        accx += v0 * __uint_as_float(u0 << 16) + v1 * __uint_as_float(u1 << 16)
              + v2 * __uint_as_float(u2 << 16) + v3 * __uint_as_float(u3 << 16);
        accy += v0 * __uint_as_float(u0 & 0xffff0000u) + v1 * __uint_as_float(u1 & 0xffff0000u)
              + v2 * __uint_as_float(u2 & 0xffff0000u) + v3 * __uint_as_float(u3 & 0xffff0000u);
    }
    for (; e < e1; ++e) {
        int cc = col[e];
        float v = dinv[cc];
        unsigned int u = H[(size_t)cc * 64 + lane];
        accx += v * __uint_as_float(u << 16);
        accy += v * __uint_as_float(u & 0xffff0000u);
    }
    accx = fmaxf(accx * di, 0.f);
    accy = fmaxf(accy * di, 0.f);
    *(__hip_bfloat162*)&out[(size_t)i * 128 + 2 * lane] =
        __float22bfloat162_rn(make_float2(accx, accy));
}

// ---------------------------------------------------------------------------
// SpMM (CSR, wave-per-row), F=64, bf16 H, fused log_softmax, fp32 out.
// ---------------------------------------------------------------------------
__global__ __launch_bounds__(256) void spmm_logsoftmax_64(const int* __restrict__ row_ptr,
                                                          const int* __restrict__ col,
                                                          const float* __restrict__ dinv,
                                                          const unsigned short* __restrict__ H, // bf16
                                                          float* __restrict__ out, int N) {
    int wave = threadIdx.x >> 6;
    int lane = threadIdx.x & 63;
    int i = blockIdx.x * 4 + wave;
    if (i >= N) return;
    float di = dinv[i];
    int e0 = row_ptr[i], e1 = row_ptr[i + 1];
    float acc = 0.f;
    int e = e0;
    for (; e + 4 <= e1; e += 4) {
        int c0 = col[e + 0], c1 = col[e + 1], c2 = col[e + 2], c3 = col[e + 3];
        float v0 = dinv[c0], v1 = dinv[c1], v2 = dinv[c2], v3 = dinv[c3];
        float h0 = __uint_as_float((unsigned int)H[(size_t)c0 * 64 + lane] << 16);
        float h1 = __uint_as_float((unsigned int)H[(size_t)c1 * 64 + lane] << 16);
        float h2 = __uint_as_float((unsigned int)H[(size_t)c2 * 64 + lane] << 16);
        float h3 = __uint_as_float((unsigned int)H[(size_t)c3 * 64 + lane] << 16);
        acc += v0 * h0 + v1 * h1 + v2 * h2 + v3 * h3;
    }
    for (; e < e1; ++e) {
        int cc = col[e];
        acc += dinv[cc] * __uint_as_float((unsigned int)H[(size_t)cc * 64 + lane] << 16);
    }
    acc *= di;
    float m = acc;
#pragma unroll
    for (int off = 32; off > 0; off >>= 1)
        m = fmaxf(m, __shfl_xor(m, off, 64));
    float ex = __expf(acc - m);
    float s = ex;
#pragma unroll
    for (int off = 32; off > 0; off >>= 1)
        s += __shfl_xor(s, off, 64);
    out[(size_t)i * 64 + lane] = acc - m - __logf(s);
}

// ---------------------------------------------------------------------------
extern "C" void kernel_launch(void* const* d_in, const int* in_sizes, int n_in,
                              void* d_out, int out_size, void* d_ws, size_t ws_size,
                              hipStream_t stream) {
    const float* x    = (const float*)d_in[0];
    const int*   erow = (const int*)d_in[1];
    const int*   ecol = (const int*)d_in[2];
    const float* W0   = (const float*)d_in[3];
    const float* b0   = (const float*)d_in[4];
    const float* W1   = (const float*)d_in[5];
    const float* b1   = (const float*)d_in[6];
    float* out = (float*)d_out;

    char* ws = (char*)d_ws;
    // layout (bytes):
    //   [0, 512K)            row_ptr (100001 int)
    //   [512K, 1M)           dinv (100000 f32)
    //   [1M, +25.6M)         h0b  bf16 100000*128
    //   [27M, +25.6M)        h1b  bf16 100000*128
    //   [53M, +12.8M)        h2b  bf16 100000*64
    //   [66M, +32K)          Wt0  bf16 128*128  (as [n][k])
    //   [66.1M, +16K)        Wt1  bf16 64*128   (as [n][k])
    int*             row_ptr = (int*)ws;
    float*           dinv    = (float*)(ws + (512u << 10));
    __hip_bfloat16*  h0b     = (__hip_bfloat16*)(ws + (1u << 20));
    __hip_bfloat16*  h1b     = (__hip_bfloat16*)(ws + 27000000u);
    __hip_bfloat16*  h2b     = (__hip_bfloat16*)(ws + 53000000u);
    __hip_bfloat16*  Wt0     = (__hip_bfloat16*)(ws + 66000000u);
    __hip_bfloat16*  Wt1     = (__hip_bfloat16*)(ws + 66100000u);

    build_rowptr<<<(NE + 255) / 256, 256, 0, stream>>>(erow, row_ptr, NE, NN);
    compute_dinv<<<(NN + 255) / 256, 256, 0, stream>>>(row_ptr, dinv, NN);
    pack_wt<<<(128 * 128 + 255) / 256, 256, 0, stream>>>(W0, Wt0, 128, 128);
    pack_wt<<<(128 * 64 + 255) / 256, 256, 0, stream>>>(W1, Wt1, 128, 64);

    // h0b = bf16(x @ W0 + b0)            [MFMA]
    gemm_mfma<128, float><<<(NN + 63) / 64, 256, 0, stream>>>(x, Wt0, b0, h0b, NN);
    // h1b = bf16(relu(spmm(h0b)))
    spmm_relu_128<<<(NN + 3) / 4, 256, 0, stream>>>(row_ptr, ecol, dinv,
                                                    (const unsigned int*)h0b, h1b, NN);
    // h2b = bf16(h1b @ W1 + b1)          [MFMA]
    gemm_mfma<64, __hip_bfloat16><<<(NN + 63) / 64, 256, 0, stream>>>(h1b, Wt1, b1, h2b, NN);
    // out = log_softmax(spmm(h2b))
    spmm_logsoftmax_64<<<(NN + 3) / 4, 256, 0, stream>>>(row_ptr, ecol, dinv,
                                                         (const unsigned short*)h2b, out, NN);
}

// Round 5
// 254.092 us; speedup vs baseline: 2.1158x; 1.1123x over previous
//
#include <hip/hip_runtime.h>
#include <hip/hip_bf16.h>

#define NN 100000
#define NE 1600000

typedef __bf16 bf16x8 __attribute__((ext_vector_type(8)));
typedef float  f32x4  __attribute__((ext_vector_type(4)));

// ---------------------------------------------------------------------------
// Build CSR row_ptr from sorted edge_row. row_ptr[i] = first e with row[e]>=i.
// ---------------------------------------------------------------------------
__global__ __launch_bounds__(256) void build_rowptr(const int* __restrict__ row,
                                                    int* __restrict__ row_ptr,
                                                    int E, int N) {
    int e = blockIdx.x * blockDim.x + threadIdx.x;
    if (e >= E) return;
    int r  = row[e];
    int rp = (e == 0) ? -1 : row[e - 1];
    for (int i = rp + 1; i <= r; ++i) row_ptr[i] = e;
    if (e == E - 1) {
        for (int i = r + 1; i <= N; ++i) row_ptr[i] = E;
    }
}

// dinv[i] = deg>0 ? rsqrt(deg) : 0
__global__ __launch_bounds__(256) void compute_dinv(const int* __restrict__ row_ptr,
                                                    float* __restrict__ dinv, int N) {
    int i = blockIdx.x * blockDim.x + threadIdx.x;
    if (i >= N) return;
    int deg = row_ptr[i + 1] - row_ptr[i];
    dinv[i] = (deg > 0) ? rsqrtf((float)deg) : 0.0f;
}

// Wt[n][k] = bf16(W[k][n])  — B-operand layout, k contiguous.
__global__ __launch_bounds__(256) void pack_wt(const float* __restrict__ W,
                                               __hip_bfloat16* __restrict__ Wt,
                                               int K, int N) {
    int idx = blockIdx.x * 256 + threadIdx.x;
    if (idx >= K * N) return;
    int n = idx / K, k = idx - n * K;
    Wt[idx] = __float2bfloat16(W[(size_t)k * N + n]);
}

// ---------------------------------------------------------------------------
// MFMA bf16 GEMM: out[M,NO] = rowscale[r] * (X[M,128] @ Wt^T + bias), bf16 out.
// Pre-scaling by dinv[r] lets the SpMM drop its per-edge dinv[col] gather.
// ---------------------------------------------------------------------------
template <int NO, typename InT>
__global__ __launch_bounds__(256) void gemm_mfma(const InT* __restrict__ X,
                                                 const __hip_bfloat16* __restrict__ Wt,
                                                 const float* __restrict__ bias,
                                                 const float* __restrict__ rowscale,
                                                 __hip_bfloat16* __restrict__ out, int M) {
    constexpr int LDA = 136;     // padded LDS row stride (shorts)
    constexpr int NT  = NO / 16; // n-tiles per wave
    __shared__ short As[64 * LDA];
    __shared__ short Ws[NO * LDA];

    const int t = threadIdx.x;
    const int w = t >> 6, lane = t & 63;
    const int l15 = lane & 15, quad = lane >> 4;
    const int rbase = blockIdx.x * 64;

    // stage Wt (NO x 128 bf16) -> Ws
    for (int i = t; i < NO * 16; i += 256) {
        int n = i >> 4, c8 = (i & 15) << 3;
        *(uint4*)&Ws[n * LDA + c8] = ((const uint4*)Wt)[i];
    }
    // stage A tile (64 x 128) -> As (bf16)
    if constexpr (sizeof(InT) == 4) {
        for (int i = t; i < 2048; i += 256) {       // 64 rows x 32 float4
            int r = i >> 5, c = (i & 31) << 2;      // c in shorts
            float4 xv = make_float4(0.f, 0.f, 0.f, 0.f);
            if (rbase + r < M) xv = ((const float4*)X)[(size_t)rbase * 32 + i];
            union { __hip_bfloat162 h; unsigned int u; } p0, p1;
            p0.h = __float22bfloat162_rn(make_float2(xv.x, xv.y));
            p1.h = __float22bfloat162_rn(make_float2(xv.z, xv.w));
            *(uint2*)&As[r * LDA + c] = make_uint2(p0.u, p1.u);
        }
    } else {
        for (int i = t; i < 1024; i += 256) {       // 64 rows x 16 uint4
            int r = i >> 4, c8 = (i & 15) << 3;
            uint4 v = make_uint4(0u, 0u, 0u, 0u);
            if (rbase + r < M) v = ((const uint4*)X)[(size_t)rbase * 16 + i];
            *(uint4*)&As[r * LDA + c8] = v;
        }
    }
    __syncthreads();

    f32x4 acc[NT];
#pragma unroll
    for (int nt = 0; nt < NT; ++nt) {
        float bv = bias[nt * 16 + l15];
        acc[nt][0] = bv; acc[nt][1] = bv; acc[nt][2] = bv; acc[nt][3] = bv;
    }

    const int arow = w * 16 + l15;
#pragma unroll
    for (int kc = 0; kc < 4; ++kc) {
        bf16x8 af = *(const bf16x8*)&As[arow * LDA + kc * 32 + quad * 8];
#pragma unroll
        for (int nt = 0; nt < NT; ++nt) {
            bf16x8 bfr = *(const bf16x8*)&Ws[(nt * 16 + l15) * LDA + kc * 32 + quad * 8];
            acc[nt] = __builtin_amdgcn_mfma_f32_16x16x32_bf16(af, bfr, acc[nt], 0, 0, 0);
        }
    }

#pragma unroll
    for (int r = 0; r < 4; ++r) {
        int grow = rbase + w * 16 + quad * 4 + r;
        if (grow < M) {
            float sc = rowscale[grow];
#pragma unroll
            for (int nt = 0; nt < NT; ++nt)
                out[(size_t)grow * NO + nt * 16 + l15] = __float2bfloat16(acc[nt][r] * sc);
        }
    }
}

// ---------------------------------------------------------------------------
// SpMM (CSR, wave-per-row), F=128, bf16 H (pre-scaled by dinv[col]), relu,
// bf16 out. Row index forced wave-uniform -> col[] via s_load, H gather via
// scalar base + lane offset: zero per-edge vector addr arithmetic.
// ---------------------------------------------------------------------------
__global__ __launch_bounds__(256) void spmm_relu_128(const int* __restrict__ row_ptr,
                                                     const int* __restrict__ col,
                                                     const float* __restrict__ dinv,
                                                     const unsigned int* __restrict__ H, // bf16x2
                                                     __hip_bfloat16* __restrict__ out, int N) {
    const int lane = threadIdx.x & 63;
    int i = __builtin_amdgcn_readfirstlane(blockIdx.x * 4 + (threadIdx.x >> 6));
    if (i >= N) return;
    const float di = dinv[i];
    const int e0 = __builtin_amdgcn_readfirstlane(row_ptr[i]);
    const int e1 = __builtin_amdgcn_readfirstlane(row_ptr[i + 1]);
    float accx = 0.f, accy = 0.f;
    int e = e0;
    for (; e + 8 <= e1; e += 8) {
#pragma unroll
        for (int j = 0; j < 8; ++j) {
            int c = __builtin_amdgcn_readfirstlane(col[e + j]);
            unsigned int u = H[(size_t)c * 64 + lane];
            accx += __uint_as_float(u << 16);
            accy += __uint_as_float(u & 0xffff0000u);
        }
    }
    for (; e < e1; ++e) {
        int c = __builtin_amdgcn_readfirstlane(col[e]);
        unsigned int u = H[(size_t)c * 64 + lane];
        accx += __uint_as_float(u << 16);
        accy += __uint_as_float(u & 0xffff0000u);
    }
    accx = fmaxf(accx * di, 0.f);
    accy = fmaxf(accy * di, 0.f);
    *(__hip_bfloat162*)&out[(size_t)i * 128 + 2 * lane] =
        __float22bfloat162_rn(make_float2(accx, accy));
}

// ---------------------------------------------------------------------------
// SpMM (CSR, wave-per-row), F=64, bf16 H (pre-scaled), fused log_softmax.
// ---------------------------------------------------------------------------
__global__ __launch_bounds__(256) void spmm_logsoftmax_64(const int* __restrict__ row_ptr,
                                                          const int* __restrict__ col,
                                                          const float* __restrict__ dinv,
                                                          const unsigned short* __restrict__ H, // bf16
                                                          float* __restrict__ out, int N) {
    const int lane = threadIdx.x & 63;
    int i = __builtin_amdgcn_readfirstlane(blockIdx.x * 4 + (threadIdx.x >> 6));
    if (i >= N) return;
    const float di = dinv[i];
    const int e0 = __builtin_amdgcn_readfirstlane(row_ptr[i]);
    const int e1 = __builtin_amdgcn_readfirstlane(row_ptr[i + 1]);
    float acc = 0.f;
    int e = e0;
    for (; e + 8 <= e1; e += 8) {
#pragma unroll
        for (int j = 0; j < 8; ++j) {
            int c = __builtin_amdgcn_readfirstlane(col[e + j]);
            acc += __uint_as_float((unsigned int)H[(size_t)c * 64 + lane] << 16);
        }
    }
    for (; e < e1; ++e) {
        int c = __builtin_amdgcn_readfirstlane(col[e]);
        acc += __uint_as_float((unsigned int)H[(size_t)c * 64 + lane] << 16);
    }
    acc *= di;
    float m = acc;
#pragma unroll
    for (int off = 32; off > 0; off >>= 1)
        m = fmaxf(m, __shfl_xor(m, off, 64));
    float ex = __expf(acc - m);
    float s = ex;
#pragma unroll
    for (int off = 32; off > 0; off >>= 1)
        s += __shfl_xor(s, off, 64);
    out[(size_t)i * 64 + lane] = acc - m - __logf(s);
}

// ---------------------------------------------------------------------------
extern "C" void kernel_launch(void* const* d_in, const int* in_sizes, int n_in,
                              void* d_out, int out_size, void* d_ws, size_t ws_size,
                              hipStream_t stream) {
    const float* x    = (const float*)d_in[0];
    const int*   erow = (const int*)d_in[1];
    const int*   ecol = (const int*)d_in[2];
    const float* W0   = (const float*)d_in[3];
    const float* b0   = (const float*)d_in[4];
    const float* W1   = (const float*)d_in[5];
    const float* b1   = (const float*)d_in[6];
    float* out = (float*)d_out;

    char* ws = (char*)d_ws;
    // layout (bytes):
    //   [0, 512K)            row_ptr (100001 int)
    //   [512K, 1M)           dinv (100000 f32)  + ones scale at [768K]
    //   [1M, +25.6M)         h0b  bf16 100000*128   (pre-scaled by dinv[row])
    //   [27M, +25.6M)        h1b  bf16 100000*128
    //   [53M, +12.8M)        h2b  bf16 100000*64    (pre-scaled by dinv[row])
    //   [66M, +32K)          Wt0  bf16 128*128 (as [n][k])
    //   [66.1M, +16K)        Wt1  bf16 64*128  (as [n][k])
    int*             row_ptr = (int*)ws;
    float*           dinv    = (float*)(ws + (512u << 10));
    __hip_bfloat16*  h0b     = (__hip_bfloat16*)(ws + (1u << 20));
    __hip_bfloat16*  h1b     = (__hip_bfloat16*)(ws + 27000000u);
    __hip_bfloat16*  h2b     = (__hip_bfloat16*)(ws + 53000000u);
    __hip_bfloat16*  Wt0     = (__hip_bfloat16*)(ws + 66000000u);
    __hip_bfloat16*  Wt1     = (__hip_bfloat16*)(ws + 66100000u);

    build_rowptr<<<(NE + 255) / 256, 256, 0, stream>>>(erow, row_ptr, NE, NN);
    compute_dinv<<<(NN + 255) / 256, 256, 0, stream>>>(row_ptr, dinv, NN);
    pack_wt<<<(128 * 128 + 255) / 256, 256, 0, stream>>>(W0, Wt0, 128, 128);
    pack_wt<<<(128 * 64 + 255) / 256, 256, 0, stream>>>(W1, Wt1, 128, 64);

    // h0b = bf16(dinv[r] * (x @ W0 + b0))           [MFMA, pre-scaled]
    gemm_mfma<128, float><<<(NN + 63) / 64, 256, 0, stream>>>(x, Wt0, b0, dinv, h0b, NN);
    // h1b = bf16(relu(di * sum H[col]))
    spmm_relu_128<<<(NN + 3) / 4, 256, 0, stream>>>(row_ptr, ecol, dinv,
                                                    (const unsigned int*)h0b, h1b, NN);
    // h2b = bf16(dinv[r] * (h1b @ W1 + b1))         [MFMA, pre-scaled]
    gemm_mfma<64, __hip_bfloat16><<<(NN + 63) / 64, 256, 0, stream>>>(h1b, Wt1, b1, dinv, h2b, NN);
    // out = log_softmax(di * sum H[col])
    spmm_logsoftmax_64<<<(NN + 3) / 4, 256, 0, stream>>>(row_ptr, ecol, dinv,
                                                         (const unsigned short*)h2b, out, NN);
}

// Round 6
// 249.121 us; speedup vs baseline: 2.1580x; 1.0200x over previous
//
#include <hip/hip_runtime.h>
#include <hip/hip_bf16.h>

#define NN 100000
#define NE 1600000

typedef __bf16 bf16x8 __attribute__((ext_vector_type(8)));
typedef float  f32x4  __attribute__((ext_vector_type(4)));

// ---------------------------------------------------------------------------
// Build CSR row_ptr from sorted edge_row. row_ptr[i] = first e with row[e]>=i.
// ---------------------------------------------------------------------------
__global__ __launch_bounds__(256) void build_rowptr(const int* __restrict__ row,
                                                    int* __restrict__ row_ptr,
                                                    int E, int N) {
    int e = blockIdx.x * blockDim.x + threadIdx.x;
    if (e >= E) return;
    int r  = row[e];
    int rp = (e == 0) ? -1 : row[e - 1];
    for (int i = rp + 1; i <= r; ++i) row_ptr[i] = e;
    if (e == E - 1) {
        for (int i = r + 1; i <= N; ++i) row_ptr[i] = E;
    }
}

// dinv[i] = deg>0 ? rsqrt(deg) : 0
__global__ __launch_bounds__(256) void compute_dinv(const int* __restrict__ row_ptr,
                                                    float* __restrict__ dinv, int N) {
    int i = blockIdx.x * blockDim.x + threadIdx.x;
    if (i >= N) return;
    int deg = row_ptr[i + 1] - row_ptr[i];
    dinv[i] = (deg > 0) ? rsqrtf((float)deg) : 0.0f;
}

// Pack both weight matrices to bf16 [n][k] (B-operand layout) in one launch.
__global__ __launch_bounds__(256) void pack_weights(const float* __restrict__ W0,
                                                    const float* __restrict__ W1,
                                                    __hip_bfloat16* __restrict__ Wt0,
                                                    __hip_bfloat16* __restrict__ Wt1) {
    int idx = blockIdx.x * 256 + threadIdx.x;
    if (idx < 128 * 128) {
        int n = idx >> 7, k = idx & 127;
        Wt0[idx] = __float2bfloat16(W0[(size_t)k * 128 + n]);
    } else if (idx < 128 * 128 + 64 * 128) {
        int r = idx - 128 * 128;
        int n = r >> 7, k = r & 127;
        Wt1[r] = __float2bfloat16(W1[(size_t)k * 64 + n]);
    }
}

// ---------------------------------------------------------------------------
// MFMA bf16 GEMM: out[M,NO] = rowscale[r] * (X[M,128] @ Wt^T + bias), bf16 out.
// BM=128 rows/block, 512 threads (8 waves), wave w owns rows w*16..+16.
// LDS XOR-swizzle (granule g at phys g^(row&7)) -> conflict-free b128 reads
// with zero padding: As 32KB + Ws 32/16KB (<=64KB, 2-3 blocks/CU).
// Epilogue: C-frags -> wave-local LDS rows (no barrier) -> coalesced uint4.
// Fragment layouts (m89-verified): A[m=lane&15][k=quad*8+j],
// B[n=lane&15][k=quad*8+j], C[row=quad*4+reg][col=lane&15].
// ---------------------------------------------------------------------------
template <int NO, typename InT>
__global__ __launch_bounds__(512) void gemm_mfma(const InT* __restrict__ X,
                                                 const __hip_bfloat16* __restrict__ Wt,
                                                 const float* __restrict__ bias,
                                                 const float* __restrict__ rowscale,
                                                 __hip_bfloat16* __restrict__ out, int M) {
    constexpr int NT = NO / 16;
    __shared__ unsigned short As[128 * 128];
    __shared__ unsigned short Ws[NO * 128];

    const int t = threadIdx.x;
    const int w = t >> 6, lane = t & 63;
    const int l15 = lane & 15, quad = lane >> 4;
    const int rbase = blockIdx.x * 128;

    // stage Wt (NO x 128 bf16) -> Ws, swizzled
    for (int i = t; i < NO * 16; i += 512) {
        int n = i >> 4, g = i & 15;
        *(uint4*)&Ws[n * 128 + ((g ^ (n & 7)) << 3)] = ((const uint4*)Wt)[i];
    }
    // stage A tile (128 x 128) -> As (bf16, swizzled)
    if constexpr (sizeof(InT) == 4) {
        for (int i = t; i < 4096; i += 512) {        // 128 rows x 32 float4
            int r = i >> 5, c2 = i & 31;             // c2: float4 chunk (4 shorts)
            float4 xv = make_float4(0.f, 0.f, 0.f, 0.f);
            if (rbase + r < M) xv = ((const float4*)X)[(size_t)rbase * 32 + i];
            union { __hip_bfloat162 h; unsigned int u; } p0, p1;
            p0.h = __float22bfloat162_rn(make_float2(xv.x, xv.y));
            p1.h = __float22bfloat162_rn(make_float2(xv.z, xv.w));
            int phys = ((c2 >> 1) ^ (r & 7));
            *(uint2*)&As[r * 128 + (phys << 3) + ((c2 & 1) << 2)] = make_uint2(p0.u, p1.u);
        }
    } else {
        for (int i = t; i < 2048; i += 512) {        // 128 rows x 16 uint4
            int r = i >> 4, g = i & 15;
            uint4 v = make_uint4(0u, 0u, 0u, 0u);
            if (rbase + r < M) v = ((const uint4*)X)[(size_t)rbase * 16 + i];
            *(uint4*)&As[r * 128 + ((g ^ (r & 7)) << 3)] = v;
        }
    }
    __syncthreads();

    f32x4 acc[NT];
#pragma unroll
    for (int nt = 0; nt < NT; ++nt) {
        float bv = bias[nt * 16 + l15];
        acc[nt][0] = bv; acc[nt][1] = bv; acc[nt][2] = bv; acc[nt][3] = bv;
    }

    const int arow = w * 16 + l15;
    const int asw  = arow & 7;
#pragma unroll
    for (int kc = 0; kc < 4; ++kc) {
        bf16x8 af = *(const bf16x8*)&As[arow * 128 + (((kc * 4 + quad) ^ asw) << 3)];
#pragma unroll
        for (int nt = 0; nt < NT; ++nt) {
            int brow = nt * 16 + l15;
            bf16x8 bfr = *(const bf16x8*)&Ws[brow * 128 + (((kc * 4 + quad) ^ (brow & 7)) << 3)];
            acc[nt] = __builtin_amdgcn_mfma_f32_16x16x32_bf16(af, bfr, acc[nt], 0, 0, 0);
        }
    }

    // epilogue: C -> wave-local LDS rows (swizzled bf16), then coalesced stores
    __hip_bfloat16* Cs = (__hip_bfloat16*)As;
#pragma unroll
    for (int r4 = 0; r4 < 4; ++r4) {
        int lrow = w * 16 + quad * 4 + r4;
        int grow = rbase + lrow;
        float sc = (grow < M) ? rowscale[grow] : 0.f;
#pragma unroll
        for (int nt = 0; nt < NT; ++nt) {
            int ct = nt * 16 + l15;
            Cs[lrow * 128 + ((((ct >> 3) ^ (lrow & 7)) << 3)) + (ct & 7)] =
                __float2bfloat16(acc[nt][r4] * sc);
        }
    }
    // wave-local RAW on LDS: compiler inserts lgkmcnt wait; no barrier needed
    constexpr int RJ  = NO / 8;           // uint4 granules per row
    constexpr int CNT = (16 * RJ) / 64;   // per-lane store count
#pragma unroll
    for (int k = 0; k < CNT; ++k) {
        int idx = k * 64 + lane;
        int lr16 = idx / RJ, j = idx % RJ;
        int lrow = w * 16 + lr16;
        int grow = rbase + lrow;
        if (grow < M) {
            uint4 v = *(const uint4*)&Cs[lrow * 128 + ((j ^ (lrow & 7)) << 3)];
            *(uint4*)&out[(size_t)grow * NO + (j << 3)] = v;
        }
    }
}

// ---------------------------------------------------------------------------
// SpMM (CSR, wave-per-row), F=128, bf16 H (pre-scaled by dinv[col]), relu,
// bf16 out. Wave-uniform row -> col via s_load; 16 outstanding gathers.
// ---------------------------------------------------------------------------
__global__ __launch_bounds__(256) void spmm_relu_128(const int* __restrict__ row_ptr,
                                                     const int* __restrict__ col,
                                                     const float* __restrict__ dinv,
                                                     const unsigned int* __restrict__ H, // bf16x2
                                                     __hip_bfloat16* __restrict__ out, int N) {
    const int lane = threadIdx.x & 63;
    int i = __builtin_amdgcn_readfirstlane(blockIdx.x * 4 + (threadIdx.x >> 6));
    if (i >= N) return;
    const float di = dinv[i];
    const int e0 = __builtin_amdgcn_readfirstlane(row_ptr[i]);
    const int e1 = __builtin_amdgcn_readfirstlane(row_ptr[i + 1]);
    float accx = 0.f, accy = 0.f;
    int e = e0;
    for (; e + 16 <= e1; e += 16) {
        unsigned int u[16];
#pragma unroll
        for (int j = 0; j < 16; ++j) {
            int c = __builtin_amdgcn_readfirstlane(col[e + j]);
            u[j] = H[(size_t)c * 64 + lane];
        }
#pragma unroll
        for (int j = 0; j < 16; ++j) {
            accx += __uint_as_float(u[j] << 16);
            accy += __uint_as_float(u[j] & 0xffff0000u);
        }
    }
    for (; e + 8 <= e1; e += 8) {
        unsigned int u[8];
#pragma unroll
        for (int j = 0; j < 8; ++j) {
            int c = __builtin_amdgcn_readfirstlane(col[e + j]);
            u[j] = H[(size_t)c * 64 + lane];
        }
#pragma unroll
        for (int j = 0; j < 8; ++j) {
            accx += __uint_as_float(u[j] << 16);
            accy += __uint_as_float(u[j] & 0xffff0000u);
        }
    }
    for (; e < e1; ++e) {
        int c = __builtin_amdgcn_readfirstlane(col[e]);
        unsigned int u = H[(size_t)c * 64 + lane];
        accx += __uint_as_float(u << 16);
        accy += __uint_as_float(u & 0xffff0000u);
    }
    accx = fmaxf(accx * di, 0.f);
    accy = fmaxf(accy * di, 0.f);
    *(__hip_bfloat162*)&out[(size_t)i * 128 + 2 * lane] =
        __float22bfloat162_rn(make_float2(accx, accy));
}

// ---------------------------------------------------------------------------
// SpMM (CSR, wave-per-row), F=64, bf16 H (pre-scaled), fused log_softmax.
// ---------------------------------------------------------------------------
__global__ __launch_bounds__(256) void spmm_logsoftmax_64(const int* __restrict__ row_ptr,
                                                          const int* __restrict__ col,
                                                          const float* __restrict__ dinv,
                                                          const unsigned short* __restrict__ H, // bf16
                                                          float* __restrict__ out, int N) {
    const int lane = threadIdx.x & 63;
    int i = __builtin_amdgcn_readfirstlane(blockIdx.x * 4 + (threadIdx.x >> 6));
    if (i >= N) return;
    const float di = dinv[i];
    const int e0 = __builtin_amdgcn_readfirstlane(row_ptr[i]);
    const int e1 = __builtin_amdgcn_readfirstlane(row_ptr[i + 1]);
    float acc = 0.f;
    int e = e0;
    for (; e + 16 <= e1; e += 16) {
        unsigned short u[16];
#pragma unroll
        for (int j = 0; j < 16; ++j) {
            int c = __builtin_amdgcn_readfirstlane(col[e + j]);
            u[j] = H[(size_t)c * 64 + lane];
        }
#pragma unroll
        for (int j = 0; j < 16; ++j)
            acc += __uint_as_float((unsigned int)u[j] << 16);
    }
    for (; e + 8 <= e1; e += 8) {
        unsigned short u[8];
#pragma unroll
        for (int j = 0; j < 8; ++j) {
            int c = __builtin_amdgcn_readfirstlane(col[e + j]);
            u[j] = H[(size_t)c * 64 + lane];
        }
#pragma unroll
        for (int j = 0; j < 8; ++j)
            acc += __uint_as_float((unsigned int)u[j] << 16);
    }
    for (; e < e1; ++e) {
        int c = __builtin_amdgcn_readfirstlane(col[e]);
        acc += __uint_as_float((unsigned int)H[(size_t)c * 64 + lane] << 16);
    }
    acc *= di;
    float m = acc;
#pragma unroll
    for (int off = 32; off > 0; off >>= 1)
        m = fmaxf(m, __shfl_xor(m, off, 64));
    float ex = __expf(acc - m);
    float s = ex;
#pragma unroll
    for (int off = 32; off > 0; off >>= 1)
        s += __shfl_xor(s, off, 64);
    out[(size_t)i * 64 + lane] = acc - m - __logf(s);
}

// ---------------------------------------------------------------------------
extern "C" void kernel_launch(void* const* d_in, const int* in_sizes, int n_in,
                              void* d_out, int out_size, void* d_ws, size_t ws_size,
                              hipStream_t stream) {
    const float* x    = (const float*)d_in[0];
    const int*   erow = (const int*)d_in[1];
    const int*   ecol = (const int*)d_in[2];
    const float* W0   = (const float*)d_in[3];
    const float* b0   = (const float*)d_in[4];
    const float* W1   = (const float*)d_in[5];
    const float* b1   = (const float*)d_in[6];
    float* out = (float*)d_out;

    char* ws = (char*)d_ws;
    // layout (bytes):
    //   [0, 512K)            row_ptr (100001 int)
    //   [512K, 1M)           dinv (100000 f32)
    //   [1M, +25.6M)         h0b  bf16 100000*128   (pre-scaled by dinv[row])
    //   [27M, +25.6M)        h1b  bf16 100000*128
    //   [53M, +12.8M)        h2b  bf16 100000*64    (pre-scaled by dinv[row])
    //   [66M, +32K)          Wt0  bf16 128*128 (as [n][k])
    //   [66.1M, +16K)        Wt1  bf16 64*128  (as [n][k])
    int*             row_ptr = (int*)ws;
    float*           dinv    = (float*)(ws + (512u << 10));
    __hip_bfloat16*  h0b     = (__hip_bfloat16*)(ws + (1u << 20));
    __hip_bfloat16*  h1b     = (__hip_bfloat16*)(ws + 27000000u);
    __hip_bfloat16*  h2b     = (__hip_bfloat16*)(ws + 53000000u);
    __hip_bfloat16*  Wt0     = (__hip_bfloat16*)(ws + 66000000u);
    __hip_bfloat16*  Wt1     = (__hip_bfloat16*)(ws + 66100000u);

    build_rowptr<<<(NE + 255) / 256, 256, 0, stream>>>(erow, row_ptr, NE, NN);
    compute_dinv<<<(NN + 255) / 256, 256, 0, stream>>>(row_ptr, dinv, NN);
    pack_weights<<<(128 * 128 + 64 * 128 + 255) / 256, 256, 0, stream>>>(W0, W1, Wt0, Wt1);

    // h0b = bf16(dinv[r] * (x @ W0 + b0))           [MFMA, BM=128]
    gemm_mfma<128, float><<<(NN + 127) / 128, 512, 0, stream>>>(x, Wt0, b0, dinv, h0b, NN);
    // h1b = bf16(relu(di * sum H[col]))
    spmm_relu_128<<<(NN + 3) / 4, 256, 0, stream>>>(row_ptr, ecol, dinv,
                                                    (const unsigned int*)h0b, h1b, NN);
    // h2b = bf16(dinv[r] * (h1b @ W1 + b1))         [MFMA, BM=128]
    gemm_mfma<64, __hip_bfloat16><<<(NN + 127) / 128, 512, 0, stream>>>(h1b, Wt1, b1, dinv, h2b, NN);
    // out = log_softmax(di * sum H[col])
    spmm_logsoftmax_64<<<(NN + 3) / 4, 256, 0, stream>>>(row_ptr, ecol, dinv,
                                                         (const unsigned short*)h2b, out, NN);
}